// Round 1
// baseline (548.753 us; speedup 1.0000x reference)
//
#include <hip/hip_runtime.h>
#include <math.h>

namespace {
constexpr int B      = 4;
constexpr int C      = 128;
constexpr int H      = 128;
constexpr int W      = 128;
constexpr int HWn    = H * W;          // 16384
constexpr int DH     = 16;
constexpr int QT     = 64;             // queries per block
constexpr int QBLK   = HWn / QT;       // 256 q-blocks per batch image
}

// ---------------------------------------------------------------------------
// Kernel 1: val[b][q][c] = sum_k nbr[b][k][q] * W_val[k][c] + b_val[c]
// Layout of val: (B, Q, C) so each head's dh=16 slice is 64B contiguous.
// ---------------------------------------------------------------------------
__global__ __launch_bounds__(256, 4) void val_gemm_kernel(
    const float* __restrict__ nbr, const float* __restrict__ Wv,
    const float* __restrict__ bv, float* __restrict__ val) {
  __shared__ float a_s[C * QT];        // a_s[k*64 + qi], 32 KB
  const int blk = blockIdx.x;
  const int b   = blk >> 8;            // QBLK == 256
  const int q0  = (blk & (QBLK - 1)) * QT;
  const int t   = threadIdx.x;

  const float* src = nbr + (size_t)b * C * HWn + q0;
#pragma unroll
  for (int i = 0; i < 8; ++i) {        // 2048 float4 loads, coalesced
    int idx = t + 256 * i;
    int k   = idx >> 4;
    int qf  = idx & 15;
    *(float4*)(&a_s[k * QT + qf * 4]) =
        *(const float4*)(src + (size_t)k * HWn + qf * 4);
  }
  __syncthreads();

  const int c0  = (t & 31) * 4;        // 4 output channels
  const int qi0 = (t >> 5) * 8;        // 8 queries
  float4 acc[8];
  const float4 bias = *(const float4*)(bv + c0);
#pragma unroll
  for (int j = 0; j < 8; ++j) acc[j] = bias;

  for (int k = 0; k < C; ++k) {
    float4 w = *(const float4*)(Wv + k * C + c0);   // coalesced across wave
#pragma unroll
    for (int j = 0; j < 8; ++j) {
      float a = a_s[k * QT + qi0 + j];
      acc[j].x += a * w.x; acc[j].y += a * w.y;
      acc[j].z += a * w.z; acc[j].w += a * w.w;
    }
  }

  float* dst = val + ((size_t)(b * HWn + q0 + qi0)) * C + c0;
#pragma unroll
  for (int j = 0; j < 8; ++j)
    *(float4*)(dst + (size_t)j * C) = acc[j];
}

// ---------------------------------------------------------------------------
// Kernel 2: off/attn projections + softmax + bilinear gather + out projection
// One block per 64 consecutive queries. Thread (qi = t&63, r = t>>6) owns
// heads {2r, 2r+1} for its query (softmax over P=8 stays in-thread).
// ---------------------------------------------------------------------------
__global__ __launch_bounds__(256) void deform_attn_kernel(
    const float* __restrict__ ext,  const float* __restrict__ flow,
    const float* __restrict__ Woff, const float* __restrict__ boff,
    const float* __restrict__ Wattn,const float* __restrict__ battn,
    const float* __restrict__ Wout, const float* __restrict__ bout,
    const float* __restrict__ val,  float* __restrict__ out) {
  // phase 1: ext_s[k*64+qi] (8192 floats). phase 2: agg_s[qi*129+c] (8256).
  __shared__ float smem[QT * 129];
  __shared__ float flow_s[2 * QT];

  const int blk = blockIdx.x;
  const int b   = blk >> 8;
  const int q0  = (blk & (QBLK - 1)) * QT;
  const int t   = threadIdx.x;

  {
    const float* esrc = ext + (size_t)b * C * HWn + q0;
#pragma unroll
    for (int i = 0; i < 8; ++i) {
      int idx = t + 256 * i;
      int k   = idx >> 4;
      int qf  = idx & 15;
      *(float4*)(&smem[k * QT + qf * 4]) =
          *(const float4*)(esrc + (size_t)k * HWn + qf * 4);
    }
    if (t < 2 * QT) {
      int comp = t >> 6;
      flow_s[t] = flow[((size_t)b * 2 + comp) * HWn + q0 + (t & 63)];
    }
  }
  __syncthreads();

  const int qi = t & 63;
  const int r  = t >> 6;               // 0..3 -> heads 2r, 2r+1

  // ---- offset + attention logits (two GEMV slices, ext broadcast from LDS)
  float offa[32];
  float atta[16];
#pragma unroll
  for (int j = 0; j < 32; ++j) offa[j] = boff[32 * r + j];
#pragma unroll
  for (int j = 0; j < 16; ++j) atta[j] = battn[16 * r + j];

  for (int k = 0; k < C; ++k) {
    float e = smem[k * QT + qi];
    const float4* wo = (const float4*)(Woff + k * 128 + 32 * r);
#pragma unroll
    for (int j4 = 0; j4 < 8; ++j4) {
      float4 w = wo[j4];
      offa[4 * j4 + 0] += e * w.x;
      offa[4 * j4 + 1] += e * w.y;
      offa[4 * j4 + 2] += e * w.z;
      offa[4 * j4 + 3] += e * w.w;
    }
    const float4* wa = (const float4*)(Wattn + k * 64 + 16 * r);
#pragma unroll
    for (int j4 = 0; j4 < 4; ++j4) {
      float4 w = wa[j4];
      atta[4 * j4 + 0] += e * w.x;
      atta[4 * j4 + 1] += e * w.y;
      atta[4 * j4 + 2] += e * w.z;
      atta[4 * j4 + 3] += e * w.w;
    }
  }

  // ---- softmax over P=8 per head (in-thread) and bounded offsets
#pragma unroll
  for (int u = 0; u < 2; ++u) {
    float m = atta[u * 8];
#pragma unroll
    for (int p = 1; p < 8; ++p) m = fmaxf(m, atta[u * 8 + p]);
    float s = 0.f;
#pragma unroll
    for (int p = 0; p < 8; ++p) {
      float ev = __expf(atta[u * 8 + p] - m);
      atta[u * 8 + p] = ev;
      s += ev;
    }
    float inv = 1.f / s;
#pragma unroll
    for (int p = 0; p < 8; ++p) atta[u * 8 + p] *= inv;
  }
#pragma unroll
  for (int j = 0; j < 32; ++j) offa[j] = 10.f * tanhf(offa[j]);

  // ---- bilinear gather + attention-weighted accumulation
  const int q = q0 + qi;
  const float xb = (float)(q & (W - 1)) + flow_s[qi];        // j + flow_x
  const float yb = (float)(q >> 7)      + flow_s[QT + qi];   // i + flow_y
  float agg[32];
#pragma unroll
  for (int j = 0; j < 32; ++j) agg[j] = 0.f;
  const float* valb = val + (size_t)b * HWn * C;

#pragma unroll
  for (int u = 0; u < 2; ++u) {
    const int h = 2 * r + u;
    const float* valh = valb + h * DH;
#pragma unroll
    for (int p = 0; p < 8; ++p) {
      float x  = xb + offa[u * 16 + 2 * p];
      float y  = yb + offa[u * 16 + 2 * p + 1];
      float x0f = floorf(x), y0f = floorf(y);
      float wx = x - x0f, wy = y - y0f;
      int x0 = (int)x0f, y0 = (int)y0f;
      int x1 = x0 + 1,   y1 = y0 + 1;
      float aw  = atta[u * 8 + p];
      float w00 = aw * (1.f - wx) * (1.f - wy);
      float w10 = aw * wx * (1.f - wy);
      float w01 = aw * (1.f - wx) * wy;
      float w11 = aw * wx * wy;
      bool vx0 = (unsigned)x0 < (unsigned)W;
      bool vx1 = (unsigned)x1 < (unsigned)W;
      bool vy0 = (unsigned)y0 < (unsigned)H;
      bool vy1 = (unsigned)y1 < (unsigned)H;
      if (!vx0) { w00 = 0.f; w01 = 0.f; }
      if (!vx1) { w10 = 0.f; w11 = 0.f; }
      if (!vy0) { w00 = 0.f; w10 = 0.f; }
      if (!vy1) { w01 = 0.f; w11 = 0.f; }
      int x0c = min(max(x0, 0), W - 1);
      int x1c = min(max(x1, 0), W - 1);
      int y0c = min(max(y0, 0), H - 1);
      int y1c = min(max(y1, 0), H - 1);
      const float* p00 = valh + (size_t)(y0c * W + x0c) * C;
      const float* p10 = valh + (size_t)(y0c * W + x1c) * C;
      const float* p01 = valh + (size_t)(y1c * W + x0c) * C;
      const float* p11 = valh + (size_t)(y1c * W + x1c) * C;
#pragma unroll
      for (int d4 = 0; d4 < 4; ++d4) {
        float4 g00 = *(const float4*)(p00 + 4 * d4);
        float4 g10 = *(const float4*)(p10 + 4 * d4);
        float4 g01 = *(const float4*)(p01 + 4 * d4);
        float4 g11 = *(const float4*)(p11 + 4 * d4);
        int o = u * 16 + 4 * d4;
        agg[o + 0] += w00 * g00.x + w10 * g10.x + w01 * g01.x + w11 * g11.x;
        agg[o + 1] += w00 * g00.y + w10 * g10.y + w01 * g01.y + w11 * g11.y;
        agg[o + 2] += w00 * g00.z + w10 * g10.z + w01 * g01.z + w11 * g11.z;
        agg[o + 3] += w00 * g00.w + w10 * g10.w + w01 * g01.w + w11 * g11.w;
      }
    }
  }

  // ---- agg -> LDS (pad 129 breaks the power-of-2 bank stride), then out-proj
  __syncthreads();   // ext_s no longer needed by anyone past this point
#pragma unroll
  for (int j = 0; j < 32; ++j) smem[qi * 129 + 32 * r + j] = agg[j];
  __syncthreads();

  const int qo0 = (t & 7) * 8;         // 8 queries
  const int c0  = (t >> 3) * 4;        // 4 channels
  float4 acc[8];
  const float4 bias = *(const float4*)(bout + c0);
#pragma unroll
  for (int j = 0; j < 8; ++j) acc[j] = bias;

  for (int k = 0; k < C; ++k) {
    float4 w = *(const float4*)(Wout + k * C + c0);
#pragma unroll
    for (int j = 0; j < 8; ++j) {
      float a = smem[(qo0 + j) * 129 + k];
      acc[j].x += a * w.x; acc[j].y += a * w.y;
      acc[j].z += a * w.z; acc[j].w += a * w.w;
    }
  }

  // out layout (B, C, H, W): out[b][c][q]
  float* ob = out + (size_t)b * C * HWn + q0 + qo0;
#pragma unroll
  for (int cc = 0; cc < 4; ++cc) {
    float4 lo, hi;
    lo.x = ((float*)&acc[0])[cc]; lo.y = ((float*)&acc[1])[cc];
    lo.z = ((float*)&acc[2])[cc]; lo.w = ((float*)&acc[3])[cc];
    hi.x = ((float*)&acc[4])[cc]; hi.y = ((float*)&acc[5])[cc];
    hi.z = ((float*)&acc[6])[cc]; hi.w = ((float*)&acc[7])[cc];
    float* orow = ob + (size_t)(c0 + cc) * HWn;
    *(float4*)(orow)     = lo;
    *(float4*)(orow + 4) = hi;
  }
}

extern "C" void kernel_launch(void* const* d_in, const int* in_sizes, int n_in,
                              void* d_out, int out_size, void* d_ws, size_t ws_size,
                              hipStream_t stream) {
  const float* nbr   = (const float*)d_in[0];
  const float* extf  = (const float*)d_in[1];
  const float* flow  = (const float*)d_in[2];
  const float* Woff  = (const float*)d_in[3];
  const float* boff  = (const float*)d_in[4];
  const float* Wattn = (const float*)d_in[5];
  const float* battn = (const float*)d_in[6];
  const float* Wval  = (const float*)d_in[7];
  const float* bval  = (const float*)d_in[8];
  const float* Wout  = (const float*)d_in[9];
  const float* bout  = (const float*)d_in[10];
  float* outp = (float*)d_out;
  float* val  = (float*)d_ws;          // B*HW*C floats = 33.5 MB

  dim3 grid(B * QBLK);                 // 1024 blocks
  dim3 block(256);
  val_gemm_kernel<<<grid, block, 0, stream>>>(nbr, Wval, bval, val);
  deform_attn_kernel<<<grid, block, 0, stream>>>(extf, flow, Woff, boff,
                                                 Wattn, battn, Wout, bout,
                                                 val, outp);
}

// Round 3
// 438.260 us; speedup vs baseline: 1.2521x; 1.2521x over previous
//
#include <hip/hip_runtime.h>
#include <math.h>

namespace {
constexpr int B    = 4;
constexpr int C    = 128;
constexpr int H    = 128;
constexpr int W    = 128;
constexpr int HWn  = H * W;            // 16384
constexpr int DH   = 16;
constexpr int QT   = 64;               // queries per block
constexpr int KC   = 16;               // k-chunk
}

__device__ __forceinline__ float fast_tanh(float x) {
  float e = __expf(2.f * x);
  return 1.f - 2.f / (e + 1.f);
}

// ---------------------------------------------------------------------------
// Kernel A: two GEMMs in one launch (concurrent blocks).
//   grp 0 (blocks 0..1023):    val[b][q][c]  = nbr^T @ W_val + b_val
//   grp 1 (blocks 1024..2047): proj[b][q][0:128] = 10*tanh(ext^T @ W_off + b_off)
//                              proj[b][q][128:192] = softmax_P(ext^T @ W_attn)
// Launched with grid=1024 (val only) when ws can't hold proj.
// ---------------------------------------------------------------------------
__global__ __launch_bounds__(256) void proj_kernel(
    const float* __restrict__ nbr,  const float* __restrict__ ext,
    const float* __restrict__ Wv,   const float* __restrict__ bv,
    const float* __restrict__ Woff, const float* __restrict__ boff,
    const float* __restrict__ Wattn,const float* __restrict__ battn,
    float* __restrict__ val, float* __restrict__ proj) {
  __shared__ float a_s[KC * QT];       // 4 KB
  __shared__ float w_s[KC * 192];      // 12 KB
  const int t   = threadIdx.x;
  const int qi  = t & 63;
  const int r   = t >> 6;
  const int grp = blockIdx.x >> 10;
  const int id  = blockIdx.x & 1023;
  const int b   = id >> 8;
  const int q0  = (id & 255) * QT;

  if (grp == 0) {
    const float* Ab = nbr + (size_t)b * C * HWn + q0;
    float acc[32];
#pragma unroll
    for (int j = 0; j < 32; ++j) acc[j] = bv[32 * r + j];

    for (int ck = 0; ck < C / KC; ++ck) {
      const int k0 = ck * KC;
      {
        int k = t >> 4, cq = (t & 15) * 4;
        *(float4*)&a_s[k * QT + cq] =
            *(const float4*)(Ab + (size_t)(k0 + k) * HWn + cq);
      }
#pragma unroll
      for (int i = 0; i < 2; ++i) {
        int idx = t + 256 * i;
        int k = idx >> 5, col = (idx & 31) * 4;
        *(float4*)&w_s[k * 128 + col] =
            *(const float4*)(Wv + (size_t)(k0 + k) * 128 + col);
      }
      __syncthreads();
#pragma unroll
      for (int k = 0; k < KC; ++k) {
        float e = a_s[k * QT + qi];
        const float4* wp = (const float4*)&w_s[k * 128 + 32 * r];
#pragma unroll
        for (int j4 = 0; j4 < 8; ++j4) {
          float4 w = wp[j4];
          acc[4 * j4 + 0] += e * w.x; acc[4 * j4 + 1] += e * w.y;
          acc[4 * j4 + 2] += e * w.z; acc[4 * j4 + 3] += e * w.w;
        }
      }
      __syncthreads();
    }
    float* dst = val + (size_t)(b * HWn + q0 + qi) * C + 32 * r;
#pragma unroll
    for (int j4 = 0; j4 < 8; ++j4)
      *(float4*)(dst + 4 * j4) = make_float4(acc[4 * j4 + 0], acc[4 * j4 + 1],
                                             acc[4 * j4 + 2], acc[4 * j4 + 3]);
  } else {
    const float* Ab = ext + (size_t)b * C * HWn + q0;
    const int base = 48 * r;
    float acc[48];
#pragma unroll
    for (int a = 0; a < 48; ++a) {
      int col = base + a;
      acc[a] = (col < 128) ? boff[col] : battn[col - 128];
    }

    for (int ck = 0; ck < C / KC; ++ck) {
      const int k0 = ck * KC;
      {
        int k = t >> 4, cq = (t & 15) * 4;
        *(float4*)&a_s[k * QT + cq] =
            *(const float4*)(Ab + (size_t)(k0 + k) * HWn + cq);
      }
#pragma unroll
      for (int i = 0; i < 3; ++i) {
        int idx = t + 256 * i;
        int k = idx / 48;
        int j = (idx % 48) * 4;
        const float* src = (j < 128)
            ? (Woff  + (size_t)(k0 + k) * 128 + j)
            : (Wattn + (size_t)(k0 + k) * 64 + (j - 128));
        *(float4*)&w_s[k * 192 + j] = *(const float4*)src;
      }
      __syncthreads();
#pragma unroll
      for (int k = 0; k < KC; ++k) {
        float e = a_s[k * QT + qi];
        const float4* wp = (const float4*)&w_s[k * 192 + base];
#pragma unroll
        for (int j4 = 0; j4 < 12; ++j4) {
          float4 w = wp[j4];
          acc[4 * j4 + 0] += e * w.x; acc[4 * j4 + 1] += e * w.y;
          acc[4 * j4 + 2] += e * w.z; acc[4 * j4 + 3] += e * w.w;
        }
      }
      __syncthreads();
    }

#pragma unroll
    for (int a = 0; a < 48; ++a)
      if (base + a < 128) acc[a] = 10.f * fast_tanh(acc[a]);
#pragma unroll
    for (int g = 0; g < 48; g += 8) {
      if (base + g >= 128) {
        float m = acc[g];
#pragma unroll
        for (int p = 1; p < 8; ++p) m = fmaxf(m, acc[g + p]);
        float s = 0.f;
#pragma unroll
        for (int p = 0; p < 8; ++p) {
          float ev = __expf(acc[g + p] - m);
          acc[g + p] = ev;
          s += ev;
        }
        float inv = 1.f / s;
#pragma unroll
        for (int p = 0; p < 8; ++p) acc[g + p] *= inv;
      }
    }

    float* dst = proj + (size_t)(b * HWn + q0 + qi) * 192 + base;
#pragma unroll
    for (int j4 = 0; j4 < 12; ++j4)
      *(float4*)(dst + 4 * j4) = make_float4(acc[4 * j4 + 0], acc[4 * j4 + 1],
                                             acc[4 * j4 + 2], acc[4 * j4 + 3]);
  }
}

// ---------------------------------------------------------------------------
// Shared device helper: bilinear gather + attention accumulate for 2 heads.
// ---------------------------------------------------------------------------
__device__ __forceinline__ void gather_heads(
    const float* __restrict__ valb, int r, float xb, float yb,
    const float* offa, const float* atta, float* agg) {
#pragma unroll
  for (int j = 0; j < 32; ++j) agg[j] = 0.f;
#pragma unroll
  for (int u = 0; u < 2; ++u) {
    const float* valh = valb + (2 * r + u) * DH;
#pragma unroll
    for (int p = 0; p < 8; ++p) {
      float x = xb + offa[u * 16 + 2 * p];
      float y = yb + offa[u * 16 + 2 * p + 1];
      float x0f = floorf(x), y0f = floorf(y);
      float wx = x - x0f, wy = y - y0f;
      int x0 = (int)x0f, y0 = (int)y0f;
      int x1 = x0 + 1,   y1 = y0 + 1;
      float aw  = atta[u * 8 + p];
      float w00 = aw * (1.f - wx) * (1.f - wy);
      float w10 = aw * wx * (1.f - wy);
      float w01 = aw * (1.f - wx) * wy;
      float w11 = aw * wx * wy;
      if ((unsigned)x0 >= (unsigned)W) { w00 = 0.f; w01 = 0.f; }
      if ((unsigned)x1 >= (unsigned)W) { w10 = 0.f; w11 = 0.f; }
      if ((unsigned)y0 >= (unsigned)H) { w00 = 0.f; w10 = 0.f; }
      if ((unsigned)y1 >= (unsigned)H) { w01 = 0.f; w11 = 0.f; }
      int x0c = min(max(x0, 0), W - 1);
      int x1c = min(max(x1, 0), W - 1);
      int y0c = min(max(y0, 0), H - 1);
      int y1c = min(max(y1, 0), H - 1);
      const float* p00 = valh + (size_t)(y0c * W + x0c) * C;
      const float* p10 = valh + (size_t)(y0c * W + x1c) * C;
      const float* p01 = valh + (size_t)(y1c * W + x0c) * C;
      const float* p11 = valh + (size_t)(y1c * W + x1c) * C;
#pragma unroll
      for (int d4 = 0; d4 < 4; ++d4) {
        float4 g00 = *(const float4*)(p00 + 4 * d4);
        float4 g10 = *(const float4*)(p10 + 4 * d4);
        float4 g01 = *(const float4*)(p01 + 4 * d4);
        float4 g11 = *(const float4*)(p11 + 4 * d4);
        int o = u * 16 + 4 * d4;
        agg[o + 0] += w00 * g00.x + w10 * g10.x + w01 * g01.x + w11 * g11.x;
        agg[o + 1] += w00 * g00.y + w10 * g10.y + w01 * g01.y + w11 * g11.y;
        agg[o + 2] += w00 * g00.z + w10 * g10.z + w01 * g01.z + w11 * g11.z;
        agg[o + 3] += w00 * g00.w + w10 * g10.w + w01 * g01.w + w11 * g11.w;
      }
    }
  }
}

// ---------------------------------------------------------------------------
// Kernel B (split path): gather (off/attn from proj ws) + out projection.
// ---------------------------------------------------------------------------
__global__ __launch_bounds__(256) void gather_out_kernel(
    const float* __restrict__ flow, const float* __restrict__ proj,
    const float* __restrict__ val,  const float* __restrict__ Wout,
    const float* __restrict__ bout, float* __restrict__ out) {
  __shared__ float agg_s[C * QT];      // 32 KB, [c][qi]
  __shared__ float w_s[KC * 128];      // 8 KB
  const int t  = threadIdx.x;
  const int qi = t & 63;
  const int r  = t >> 6;
  const int b  = blockIdx.x >> 8;
  const int q0 = (blockIdx.x & 255) * QT;
  const int q  = q0 + qi;

  const float* pp = proj + (size_t)(b * HWn + q) * 192;
  float offa[32];
  float atta[16];
#pragma unroll
  for (int j4 = 0; j4 < 8; ++j4) {
    float4 v = *(const float4*)(pp + 32 * r + 4 * j4);
    offa[4 * j4 + 0] = v.x; offa[4 * j4 + 1] = v.y;
    offa[4 * j4 + 2] = v.z; offa[4 * j4 + 3] = v.w;
  }
#pragma unroll
  for (int j4 = 0; j4 < 4; ++j4) {
    float4 v = *(const float4*)(pp + 128 + 16 * r + 4 * j4);
    atta[4 * j4 + 0] = v.x; atta[4 * j4 + 1] = v.y;
    atta[4 * j4 + 2] = v.z; atta[4 * j4 + 3] = v.w;
  }

  const float xb = (float)(q & (W - 1)) + flow[(size_t)b * 2 * HWn + q];
  const float yb = (float)((q >> 7) & (H - 1)) + flow[((size_t)b * 2 + 1) * HWn + q];

  float agg[32];
  gather_heads(val + (size_t)b * HWn * C, r, xb, yb, offa, atta, agg);

#pragma unroll
  for (int j = 0; j < 32; ++j) agg_s[(32 * r + j) * QT + qi] = agg[j];

  float acc[32];
#pragma unroll
  for (int j = 0; j < 32; ++j) acc[j] = bout[32 * r + j];

  for (int ck = 0; ck < C / KC; ++ck) {
    const int k0 = ck * KC;
#pragma unroll
    for (int i = 0; i < 2; ++i) {
      int idx = t + 256 * i;
      int k = idx >> 5, col = (idx & 31) * 4;
      *(float4*)&w_s[k * 128 + col] =
          *(const float4*)(Wout + (size_t)(k0 + k) * 128 + col);
    }
    __syncthreads();
#pragma unroll
    for (int k = 0; k < KC; ++k) {
      float a = agg_s[(k0 + k) * QT + qi];
      const float4* wp = (const float4*)&w_s[k * 128 + 32 * r];
#pragma unroll
      for (int j4 = 0; j4 < 8; ++j4) {
        float4 w = wp[j4];
        acc[4 * j4 + 0] += a * w.x; acc[4 * j4 + 1] += a * w.y;
        acc[4 * j4 + 2] += a * w.z; acc[4 * j4 + 3] += a * w.w;
      }
    }
    __syncthreads();
  }

  float* ob = out + (size_t)b * C * HWn + q0 + qi;
#pragma unroll
  for (int j = 0; j < 32; ++j)
    ob[(size_t)(32 * r + j) * HWn] = acc[j];
}

// ---------------------------------------------------------------------------
// Kernel C (fused path, ws holds only val): off/attn GEMV (LDS weights) +
// LDS round-trip of results + gather + out projection. 48 KB LDS.
// ---------------------------------------------------------------------------
__global__ __launch_bounds__(256) void fused_gather_kernel(
    const float* __restrict__ ext,  const float* __restrict__ flow,
    const float* __restrict__ Woff, const float* __restrict__ boff,
    const float* __restrict__ Wattn,const float* __restrict__ battn,
    const float* __restrict__ Wout, const float* __restrict__ bout,
    const float* __restrict__ val,  float* __restrict__ out) {
  __shared__ float smem[12288];        // 48 KB, phase-overlaid
  float* a_s = smem;                   // [KC][64]   (phase 1)
  float* w_s = smem + 1024;            // [KC][192]  (phase 1)
  // phase 2: proj_s = smem, [192][64]
  // phase 3: agg_s = smem, [128][64]; w2_s = smem + 8192, [KC][128]
  const int t  = threadIdx.x;
  const int qi = t & 63;
  const int r  = t >> 6;
  const int b  = blockIdx.x >> 8;
  const int q0 = (blockIdx.x & 255) * QT;
  const int q  = q0 + qi;

  // ---- phase 1: off/attn GEMV, thread owns cols base..base+47 for query qi
  const float* Ab = ext + (size_t)b * C * HWn + q0;
  const int base = 48 * r;
  float acc[48];
#pragma unroll
  for (int a = 0; a < 48; ++a) {
    int col = base + a;
    acc[a] = (col < 128) ? boff[col] : battn[col - 128];
  }

  for (int ck = 0; ck < C / KC; ++ck) {
    const int k0 = ck * KC;
    {
      int k = t >> 4, cq = (t & 15) * 4;
      *(float4*)&a_s[k * QT + cq] =
          *(const float4*)(Ab + (size_t)(k0 + k) * HWn + cq);
    }
#pragma unroll
    for (int i = 0; i < 3; ++i) {
      int idx = t + 256 * i;
      int k = idx / 48;
      int j = (idx % 48) * 4;
      const float* src = (j < 128)
          ? (Woff  + (size_t)(k0 + k) * 128 + j)
          : (Wattn + (size_t)(k0 + k) * 64 + (j - 128));
      *(float4*)&w_s[k * 192 + j] = *(const float4*)src;
    }
    __syncthreads();
#pragma unroll
    for (int k = 0; k < KC; ++k) {
      float e = a_s[k * QT + qi];
      const float4* wp = (const float4*)&w_s[k * 192 + base];
#pragma unroll
      for (int j4 = 0; j4 < 12; ++j4) {
        float4 w = wp[j4];
        acc[4 * j4 + 0] += e * w.x; acc[4 * j4 + 1] += e * w.y;
        acc[4 * j4 + 2] += e * w.z; acc[4 * j4 + 3] += e * w.w;
      }
    }
    __syncthreads();                   // last one also fences a_s/w_s reuse
  }

  // ---- epilogue in registers
#pragma unroll
  for (int a = 0; a < 48; ++a)
    if (base + a < 128) acc[a] = 10.f * fast_tanh(acc[a]);
#pragma unroll
  for (int g = 0; g < 48; g += 8) {
    if (base + g >= 128) {
      float m = acc[g];
#pragma unroll
      for (int p = 1; p < 8; ++p) m = fmaxf(m, acc[g + p]);
      float s = 0.f;
#pragma unroll
      for (int p = 0; p < 8; ++p) {
        float ev = __expf(acc[g + p] - m);
        acc[g + p] = ev;
        s += ev;
      }
      float inv = 1.f / s;
#pragma unroll
      for (int p = 0; p < 8; ++p) acc[g + p] *= inv;
    }
  }

  // ---- phase 2: redistribute through LDS, [col][qi] (lane-consecutive)
  float* proj_s = smem;
#pragma unroll
  for (int a = 0; a < 48; ++a) proj_s[(base + a) * QT + qi] = acc[a];
  __syncthreads();

  float offa[32];
  float atta[16];
#pragma unroll
  for (int j = 0; j < 32; ++j) offa[j] = proj_s[(32 * r + j) * QT + qi];
#pragma unroll
  for (int j = 0; j < 16; ++j) atta[j] = proj_s[(128 + 16 * r + j) * QT + qi];
  __syncthreads();                     // proj_s dead after this

  // ---- phase 3: gather + out projection
  const float xb = (float)(q & (W - 1)) + flow[(size_t)b * 2 * HWn + q];
  const float yb = (float)((q >> 7) & (H - 1)) + flow[((size_t)b * 2 + 1) * HWn + q];

  float agg[32];
  gather_heads(val + (size_t)b * HWn * C, r, xb, yb, offa, atta, agg);

  float* agg_s = smem;                 // [128][64]
  float* w2_s  = smem + 8192;          // [KC][128]
#pragma unroll
  for (int j = 0; j < 32; ++j) agg_s[(32 * r + j) * QT + qi] = agg[j];

  float acc2[32];
#pragma unroll
  for (int j = 0; j < 32; ++j) acc2[j] = bout[32 * r + j];

  for (int ck = 0; ck < C / KC; ++ck) {
    const int k0 = ck * KC;
#pragma unroll
    for (int i = 0; i < 2; ++i) {
      int idx = t + 256 * i;
      int k = idx >> 5, col = (idx & 31) * 4;
      *(float4*)&w2_s[k * 128 + col] =
          *(const float4*)(Wout + (size_t)(k0 + k) * 128 + col);
    }
    __syncthreads();
#pragma unroll
    for (int k = 0; k < KC; ++k) {
      float a = agg_s[(k0 + k) * QT + qi];
      const float4* wp = (const float4*)&w2_s[k * 128 + 32 * r];
#pragma unroll
      for (int j4 = 0; j4 < 8; ++j4) {
        float4 w = wp[j4];
        acc2[4 * j4 + 0] += a * w.x; acc2[4 * j4 + 1] += a * w.y;
        acc2[4 * j4 + 2] += a * w.z; acc2[4 * j4 + 3] += a * w.w;
      }
    }
    __syncthreads();
  }

  float* ob = out + (size_t)b * C * HWn + q0 + qi;
#pragma unroll
  for (int j = 0; j < 32; ++j)
    ob[(size_t)(32 * r + j) * HWn] = acc2[j];
}

extern "C" void kernel_launch(void* const* d_in, const int* in_sizes, int n_in,
                              void* d_out, int out_size, void* d_ws, size_t ws_size,
                              hipStream_t stream) {
  const float* nbr   = (const float*)d_in[0];
  const float* extf  = (const float*)d_in[1];
  const float* flow  = (const float*)d_in[2];
  const float* Woff  = (const float*)d_in[3];
  const float* boff  = (const float*)d_in[4];
  const float* Wattn = (const float*)d_in[5];
  const float* battn = (const float*)d_in[6];
  const float* Wval  = (const float*)d_in[7];
  const float* bval  = (const float*)d_in[8];
  const float* Wout  = (const float*)d_in[9];
  const float* bout  = (const float*)d_in[10];
  float* outp = (float*)d_out;

  const size_t val_elems  = (size_t)B * HWn * C;    // 33.5 MB
  const size_t proj_elems = (size_t)B * HWn * 192;  // 50.3 MB
  float* val  = (float*)d_ws;
  float* proj = val + val_elems;

  const bool split = ws_size >= (val_elems + proj_elems) * sizeof(float);

  if (split) {
    proj_kernel<<<dim3(2048), dim3(256), 0, stream>>>(
        nbr, extf, Wval, bval, Woff, boff, Wattn, battn, val, proj);
    gather_out_kernel<<<dim3(1024), dim3(256), 0, stream>>>(
        flow, proj, val, Wout, bout, outp);
  } else {
    // val-GEMM only (grp 0 blocks); proj arg unused there.
    proj_kernel<<<dim3(1024), dim3(256), 0, stream>>>(
        nbr, extf, Wval, bval, Woff, boff, Wattn, battn, val, val);
    fused_gather_kernel<<<dim3(1024), dim3(256), 0, stream>>>(
        extf, flow, Woff, boff, Wattn, battn, Wout, bout, val, outp);
  }
}

// Round 4
// 278.142 us; speedup vs baseline: 1.9729x; 1.5757x over previous
//
#include <hip/hip_runtime.h>
#include <math.h>

namespace {
constexpr int B    = 4;
constexpr int C    = 128;
constexpr int H    = 128;
constexpr int W    = 128;
constexpr int HWn  = H * W;            // 16384
constexpr int NH   = 8;
constexpr int KC   = 16;               // k-chunk
}

__device__ __forceinline__ float fast_tanh(float x) {
  float e = __expf(2.f * x);
  return 1.f - 2.f / (e + 1.f);
}

__device__ __forceinline__ unsigned f2bf(float f) {   // RNE to bf16 bits
  unsigned u = __float_as_uint(f);
  return (u + 0x7FFFu + ((u >> 16) & 1u)) >> 16;
}

// ---------------------------------------------------------------------------
// Kernel 1: val GEMM -> bf16 head-plane layout val[b][h][y][x][16] (32 B/px).
// 64-query strips, weights k-chunk-staged in LDS (wave-uniform broadcasts).
// ---------------------------------------------------------------------------
__global__ __launch_bounds__(256) void val_gemm_kernel(
    const float* __restrict__ nbr, const float* __restrict__ Wv,
    const float* __restrict__ bv, unsigned short* __restrict__ val) {
  __shared__ float a_s[KC * 64];       // 4 KB
  __shared__ float w_s[KC * 128];      // 8 KB
  const int t  = threadIdx.x;
  const int qi = t & 63;
  const int r  = t >> 6;
  const int b  = blockIdx.x >> 8;
  const int q0 = (blockIdx.x & 255) * 64;

  const float* Ab = nbr + (size_t)b * C * HWn + q0;
  float acc[32];
#pragma unroll
  for (int j = 0; j < 32; ++j) acc[j] = bv[32 * r + j];

  for (int ck = 0; ck < C / KC; ++ck) {
    const int k0 = ck * KC;
    {
      int k = t >> 4, cq = (t & 15) * 4;
      *(float4*)&a_s[k * 64 + cq] =
          *(const float4*)(Ab + (size_t)(k0 + k) * HWn + cq);
    }
#pragma unroll
    for (int i = 0; i < 2; ++i) {
      int idx = t + 256 * i;
      int k = idx >> 5, col = (idx & 31) * 4;
      *(float4*)&w_s[k * 128 + col] =
          *(const float4*)(Wv + (size_t)(k0 + k) * 128 + col);
    }
    __syncthreads();
#pragma unroll
    for (int k = 0; k < KC; ++k) {
      float e = a_s[k * 64 + qi];
      const float4* wp = (const float4*)&w_s[k * 128 + 32 * r];
#pragma unroll
      for (int j4 = 0; j4 < 8; ++j4) {
        float4 w = wp[j4];
        acc[4 * j4 + 0] += e * w.x; acc[4 * j4 + 1] += e * w.y;
        acc[4 * j4 + 2] += e * w.z; acc[4 * j4 + 3] += e * w.w;
      }
    }
    __syncthreads();
  }

  // store: heads 2r, 2r+1 as bf16 planes; lanes (qi) consecutive -> coalesced
#pragma unroll
  for (int u = 0; u < 2; ++u) {
    unsigned pk[8];
#pragma unroll
    for (int i = 0; i < 8; ++i) {
      unsigned lo = f2bf(acc[u * 16 + 2 * i]);
      unsigned hi = f2bf(acc[u * 16 + 2 * i + 1]);
      pk[i] = lo | (hi << 16);
    }
    unsigned short* dst =
        val + ((size_t)(b * NH + 2 * r + u) * HWn + q0 + qi) * 16;
    ((uint4*)dst)[0] = make_uint4(pk[0], pk[1], pk[2], pk[3]);
    ((uint4*)dst)[1] = make_uint4(pk[4], pk[5], pk[6], pk[7]);
  }
}

// ---------------------------------------------------------------------------
// Kernel 2: fused off/attn GEMV + bilinear gather (bf16 val) + out projection.
// 16x4 pixel tiles; XCD swizzle clusters spatial regions per-XCD for L2 reuse.
// Each thread accumulates exactly the 48 proj columns its gather needs.
// ---------------------------------------------------------------------------
__global__ __launch_bounds__(256) void fused_gather_kernel(
    const float* __restrict__ ext,  const float* __restrict__ flow,
    const float* __restrict__ Woff, const float* __restrict__ boff,
    const float* __restrict__ Wattn,const float* __restrict__ battn,
    const float* __restrict__ Wout, const float* __restrict__ bout,
    const unsigned short* __restrict__ val, float* __restrict__ out) {
  __shared__ float smem[10240];        // 40 KB
  float* a_s = smem;                   // phase 1: [KC][64]
  float* w_s = smem + 1024;            // phase 1: [KC][192]
  // phase 3: agg_s = smem [128][64]; w2_s = smem + 8192 [KC][128]

  const int t  = threadIdx.x;
  const int qi = t & 63;
  const int r  = t >> 6;

  // XCD swizzle: blk%8 = 128-tile spatial region (half a batch image)
  const int blk    = blockIdx.x;
  const int lin    = (blk & 7) * 128 + (blk >> 3);
  const int b      = lin >> 8;
  const int tile   = lin & 255;
  const int x0     = (tile & 7) * 16;
  const int y0     = (tile >> 3) * 4;
  const int xx     = qi & 15;
  const int yy     = qi >> 4;
  const int x      = x0 + xx;
  const int y      = y0 + yy;

  // ---- phase 1: off/attn GEMV. Thread owns off cols 32r..+31 (heads 2r,2r+1)
  //      and attn cols 16r..+15 — exactly its gather inputs.
  const float* Eb = ext + (size_t)b * C * HWn;
  float acc[48];
#pragma unroll
  for (int j = 0; j < 32; ++j) acc[j] = boff[32 * r + j];
#pragma unroll
  for (int j = 0; j < 16; ++j) acc[32 + j] = battn[16 * r + j];

  for (int ck = 0; ck < C / KC; ++ck) {
    const int k0 = ck * KC;
    {
      int k = t >> 4, sub = t & 15;
      int row = sub >> 2, c4 = (sub & 3) * 4;
      *(float4*)&a_s[k * 64 + row * 16 + c4] =
          *(const float4*)(Eb + (size_t)(k0 + k) * HWn + (y0 + row) * W + x0 + c4);
    }
#pragma unroll
    for (int i = 0; i < 3; ++i) {
      int idx = t + 256 * i;
      int k = idx / 48;
      int j = (idx % 48) * 4;
      const float* src = (j < 128)
          ? (Woff  + (size_t)(k0 + k) * 128 + j)
          : (Wattn + (size_t)(k0 + k) * 64 + (j - 128));
      *(float4*)&w_s[k * 192 + j] = *(const float4*)src;
    }
    __syncthreads();
#pragma unroll
    for (int k = 0; k < KC; ++k) {
      float e = a_s[k * 64 + qi];
      const float4* wo = (const float4*)&w_s[k * 192 + 32 * r];
#pragma unroll
      for (int j4 = 0; j4 < 8; ++j4) {
        float4 w = wo[j4];
        acc[4 * j4 + 0] += e * w.x; acc[4 * j4 + 1] += e * w.y;
        acc[4 * j4 + 2] += e * w.z; acc[4 * j4 + 3] += e * w.w;
      }
      const float4* wa = (const float4*)&w_s[k * 192 + 128 + 16 * r];
#pragma unroll
      for (int j4 = 0; j4 < 4; ++j4) {
        float4 w = wa[j4];
        acc[32 + 4 * j4 + 0] += e * w.x; acc[32 + 4 * j4 + 1] += e * w.y;
        acc[32 + 4 * j4 + 2] += e * w.z; acc[32 + 4 * j4 + 3] += e * w.w;
      }
    }
    __syncthreads();
  }

  // ---- epilogue: bounded offsets + per-head softmax (P=8, in-thread)
#pragma unroll
  for (int j = 0; j < 32; ++j) acc[j] = 10.f * fast_tanh(acc[j]);
#pragma unroll
  for (int u = 0; u < 2; ++u) {
    float* a = acc + 32 + 8 * u;
    float m = a[0];
#pragma unroll
    for (int p = 1; p < 8; ++p) m = fmaxf(m, a[p]);
    float s = 0.f;
#pragma unroll
    for (int p = 0; p < 8; ++p) { float ev = __expf(a[p] - m); a[p] = ev; s += ev; }
    float inv = 1.f / s;
#pragma unroll
    for (int p = 0; p < 8; ++p) a[p] *= inv;
  }

  // ---- phase 2: bilinear gather from bf16 head planes
  const float xb = (float)x + flow[(size_t)b * 2 * HWn + y * W + x];
  const float yb = (float)y + flow[((size_t)b * 2 + 1) * HWn + y * W + x];

  float agg[32];
#pragma unroll
  for (int j = 0; j < 32; ++j) agg[j] = 0.f;
  const unsigned short* valb = val + (size_t)b * NH * HWn * 16;

#pragma unroll
  for (int u = 0; u < 2; ++u) {
    const unsigned short* valh = valb + (size_t)(2 * r + u) * HWn * 16;
    float* aggh = agg + 16 * u;
#pragma unroll
    for (int p = 0; p < 8; ++p) {
      float sx = xb + acc[u * 16 + 2 * p];
      float sy = yb + acc[u * 16 + 2 * p + 1];
      float x0f = floorf(sx), y0f = floorf(sy);
      float wx = sx - x0f, wy = sy - y0f;
      int ix0 = (int)x0f, iy0 = (int)y0f;
      int ix1 = ix0 + 1,  iy1 = iy0 + 1;
      float aw  = acc[32 + u * 8 + p];
      float w00 = aw * (1.f - wx) * (1.f - wy);
      float w10 = aw * wx * (1.f - wy);
      float w01 = aw * (1.f - wx) * wy;
      float w11 = aw * wx * wy;
      if ((unsigned)ix0 >= (unsigned)W) { w00 = 0.f; w01 = 0.f; }
      if ((unsigned)ix1 >= (unsigned)W) { w10 = 0.f; w11 = 0.f; }
      if ((unsigned)iy0 >= (unsigned)H) { w00 = 0.f; w10 = 0.f; }
      if ((unsigned)iy1 >= (unsigned)H) { w01 = 0.f; w11 = 0.f; }
      int x0c = min(max(ix0, 0), W - 1);
      int x1c = min(max(ix1, 0), W - 1);
      int y0c = min(max(iy0, 0), H - 1);
      int y1c = min(max(iy1, 0), H - 1);
      const unsigned short* c00 = valh + (size_t)(y0c * W + x0c) * 16;
      const unsigned short* c10 = valh + (size_t)(y0c * W + x1c) * 16;
      const unsigned short* c01 = valh + (size_t)(y1c * W + x0c) * 16;
      const unsigned short* c11 = valh + (size_t)(y1c * W + x1c) * 16;
#pragma unroll
      for (int cn = 0; cn < 4; ++cn) {
        const unsigned short* cp = (cn == 0) ? c00 : (cn == 1) ? c10
                                  : (cn == 2) ? c01 : c11;
        float wgt = (cn == 0) ? w00 : (cn == 1) ? w10 : (cn == 2) ? w01 : w11;
        uint4 ga = ((const uint4*)cp)[0];
        uint4 gb = ((const uint4*)cp)[1];
        unsigned gs[8] = {ga.x, ga.y, ga.z, ga.w, gb.x, gb.y, gb.z, gb.w};
#pragma unroll
        for (int i = 0; i < 8; ++i) {
          float lo = __uint_as_float(gs[i] << 16);
          float hi = __uint_as_float(gs[i] & 0xFFFF0000u);
          aggh[2 * i]     += wgt * lo;
          aggh[2 * i + 1] += wgt * hi;
        }
      }
    }
  }

  // ---- phase 3: agg -> LDS [c][qi], out projection with LDS-staged Wout
  float* agg_s = smem;                 // [128][64]
  float* w2_s  = smem + 8192;          // [KC][128]
#pragma unroll
  for (int j = 0; j < 32; ++j) agg_s[(32 * r + j) * 64 + qi] = agg[j];

  float acc2[32];
#pragma unroll
  for (int j = 0; j < 32; ++j) acc2[j] = bout[32 * r + j];

  for (int ck = 0; ck < C / KC; ++ck) {
    const int k0 = ck * KC;
#pragma unroll
    for (int i = 0; i < 2; ++i) {
      int idx = t + 256 * i;
      int k = idx >> 5, col = (idx & 31) * 4;
      *(float4*)&w2_s[k * 128 + col] =
          *(const float4*)(Wout + (size_t)(k0 + k) * 128 + col);
    }
    __syncthreads();
#pragma unroll
    for (int k = 0; k < KC; ++k) {
      float a = agg_s[(k0 + k) * 64 + qi];
      const float4* wp = (const float4*)&w2_s[k * 128 + 32 * r];
#pragma unroll
      for (int j4 = 0; j4 < 8; ++j4) {
        float4 w = wp[j4];
        acc2[4 * j4 + 0] += a * w.x; acc2[4 * j4 + 1] += a * w.y;
        acc2[4 * j4 + 2] += a * w.z; acc2[4 * j4 + 3] += a * w.w;
      }
    }
    __syncthreads();
  }

  // stores: per channel, lanes cover a 16x4 tile (64 B row segments)
  float* ob = out + (size_t)b * C * HWn + y * W + x;
#pragma unroll
  for (int j = 0; j < 32; ++j)
    ob[(size_t)(32 * r + j) * HWn] = acc2[j];
}

extern "C" void kernel_launch(void* const* d_in, const int* in_sizes, int n_in,
                              void* d_out, int out_size, void* d_ws, size_t ws_size,
                              hipStream_t stream) {
  const float* nbr   = (const float*)d_in[0];
  const float* extf  = (const float*)d_in[1];
  const float* flow  = (const float*)d_in[2];
  const float* Woff  = (const float*)d_in[3];
  const float* boff  = (const float*)d_in[4];
  const float* Wattn = (const float*)d_in[5];
  const float* battn = (const float*)d_in[6];
  const float* Wval  = (const float*)d_in[7];
  const float* bval  = (const float*)d_in[8];
  const float* Wout  = (const float*)d_in[9];
  const float* bout  = (const float*)d_in[10];
  float* outp = (float*)d_out;

  unsigned short* val = (unsigned short*)d_ws;   // B*NH*HW*16 bf16 = 16.8 MB

  val_gemm_kernel<<<dim3(1024), dim3(256), 0, stream>>>(nbr, Wval, bval, val);
  fused_gather_kernel<<<dim3(1024), dim3(256), 0, stream>>>(
      extf, flow, Woff, boff, Wattn, battn, Wout, bout, val, outp);
}

// Round 5
// 233.193 us; speedup vs baseline: 2.3532x; 1.1928x over previous
//
#include <hip/hip_runtime.h>
#include <math.h>

namespace {
constexpr int B   = 4;
constexpr int C   = 128;
constexpr int H   = 128;
constexpr int W   = 128;
constexpr int HWn = H * W;           // 16384
constexpr int NH  = 8;
}

using short8 = __attribute__((ext_vector_type(8))) short;
using f32x4  = __attribute__((ext_vector_type(4))) float;

__device__ __forceinline__ float fast_tanh(float x) {
  float e = __expf(2.f * x);
  return 1.f - 2.f / (e + 1.f);
}
__device__ __forceinline__ unsigned f2bf(float f) {  // RNE bf16 bits
  unsigned u = __float_as_uint(f);
  return (u + 0x7FFFu + ((u >> 16) & 1u)) >> 16;
}
__device__ __forceinline__ unsigned pack2bf(float a, float b) {
  return f2bf(a) | (f2bf(b) << 16);
}

// ---------------------------------------------------------------------------
// Prep: bf16 transposed weights in ws.
//   wcat_t[192][128]: rows 0..127 = Woff cols, 128..191 = Wattn cols
//   wval_t[128][128], wout_t[128][128]
// ---------------------------------------------------------------------------
__global__ __launch_bounds__(256) void prep_weights_kernel(
    const float* __restrict__ Woff, const float* __restrict__ Wattn,
    const float* __restrict__ Wval, const float* __restrict__ Wout,
    unsigned short* __restrict__ wcat_t, unsigned short* __restrict__ wval_t,
    unsigned short* __restrict__ wout_t) {
  int row = blockIdx.x * 256 + threadIdx.x;
  if (row >= 448) return;
  const float* src; int ldn; int col; unsigned short* dst;
  if (row < 192) {
    if (row < 128) { src = Woff; ldn = 128; col = row; }
    else           { src = Wattn; ldn = 64; col = row - 128; }
    dst = wcat_t + row * 128;
  } else if (row < 320) {
    src = Wval; ldn = 128; col = row - 192; dst = wval_t + (row - 192) * 128;
  } else {
    src = Wout; ldn = 128; col = row - 320; dst = wout_t + (row - 320) * 128;
  }
  for (int k0 = 0; k0 < 128; k0 += 8) {
    unsigned pk[4];
#pragma unroll
    for (int j = 0; j < 4; ++j)
      pk[j] = pack2bf(src[(k0 + 2 * j) * ldn + col],
                      src[(k0 + 2 * j + 1) * ldn + col]);
    *(uint4*)(dst + k0) = make_uint4(pk[0], pk[1], pk[2], pk[3]);
  }
}

// ---------------------------------------------------------------------------
// Kernel 1: val GEMM via MFMA 16x16x32 bf16 -> val[b][h][q][16] bf16 planes.
// Block = 64 queries x 128 channels; wave w = M-tile w; N-tile n = head n.
// ---------------------------------------------------------------------------
__global__ __launch_bounds__(256) void val_gemm_kernel(
    const float* __restrict__ nbr, const unsigned short* __restrict__ wval_t,
    const float* __restrict__ bv, unsigned short* __restrict__ val) {
  __shared__ unsigned short a_s[64 * 152];   // A bf16 [q][k], reused as val_s
  __shared__ unsigned short b_s[128 * 40];   // B chunk bf16 [n][32k]
  const int t    = threadIdx.x;
  const int b    = blockIdx.x >> 8;
  const int q0   = (blockIdx.x & 255) * 64;
  const int wv   = t >> 6;
  const int lane = t & 63;
  const int li   = lane & 15, quad = lane >> 4;

  // stage A (all 128 k): nbr[k][q] fp32 -> a_s[q][k] bf16, k-pairs packed
  const float* Ab = nbr + (size_t)b * C * HWn + q0;
#pragma unroll
  for (int it = 0; it < 4; ++it) {
    int idx = t + 256 * it;              // 0..1023
    int kp  = idx >> 4;                  // k = 2kp, 2kp+1
    int q4  = (idx & 15) * 4;
    float4 fa = *(const float4*)(Ab + (size_t)(2 * kp) * HWn + q4);
    float4 fb = *(const float4*)(Ab + (size_t)(2 * kp + 1) * HWn + q4);
    const float* pa = &fa.x; const float* pb = &fb.x;
#pragma unroll
    for (int j = 0; j < 4; ++j)
      *(unsigned*)&a_s[(q4 + j) * 152 + 2 * kp] = pack2bf(pa[j], pb[j]);
  }

  f32x4 acc[8];
#pragma unroll
  for (int n = 0; n < 8; ++n) acc[n] = (f32x4){0.f, 0.f, 0.f, 0.f};

  for (int ck = 0; ck < 4; ++ck) {
    __syncthreads();
#pragma unroll
    for (int it = 0; it < 2; ++it) {
      int idx = t + 256 * it;            // 0..511
      int n = idx >> 2, seg = idx & 3;
      *(uint4*)&b_s[n * 40 + seg * 8] =
          *(const uint4*)(wval_t + n * 128 + ck * 32 + seg * 8);
    }
    __syncthreads();
    short8 af = *(const short8*)&a_s[(16 * wv + li) * 152 + ck * 32 + quad * 8];
#pragma unroll
    for (int n = 0; n < 8; ++n) {
      short8 bfr = *(const short8*)&b_s[(16 * n + li) * 40 + quad * 8];
      acc[n] = __builtin_amdgcn_mfma_f32_16x16x32_bf16(af, bfr, acc[n], 0, 0, 0);
    }
  }

  // epilogue: +bias, C-layout -> val_s[q][c] bf16 (reuse a_s), coalesced store
  __syncthreads();
#pragma unroll
  for (int n = 0; n < 8; ++n) {
    float bias = bv[16 * n + li];
#pragma unroll
    for (int reg = 0; reg < 4; ++reg) {
      int q = 16 * wv + 4 * quad + reg;
      a_s[q * 152 + 16 * n + li] = (unsigned short)f2bf(acc[n][reg] + bias);
    }
  }
  __syncthreads();
  {
    const int qi = t & 63, r = t >> 6;
    uint4 v0 = *(const uint4*)&a_s[qi * 152 + 32 * r];
    uint4 v1 = *(const uint4*)&a_s[qi * 152 + 32 * r + 8];
    uint4 v2 = *(const uint4*)&a_s[qi * 152 + 32 * r + 16];
    uint4 v3 = *(const uint4*)&a_s[qi * 152 + 32 * r + 24];
    unsigned short* d0 = val + ((size_t)(b * NH + 2 * r) * HWn + q0 + qi) * 16;
    unsigned short* d1 = val + ((size_t)(b * NH + 2 * r + 1) * HWn + q0 + qi) * 16;
    *(uint4*)d0 = v0; *(uint4*)(d0 + 8) = v1;
    *(uint4*)d1 = v2; *(uint4*)(d1 + 8) = v3;
  }
}

// ---------------------------------------------------------------------------
// Kernel 2: MFMA off/attn GEMM (split-A hi+lo) -> LDS redistribute ->
// bilinear gather (bf16 val planes) -> MFMA out-proj -> coalesced stores.
// 16x4 px tiles, XCD swizzle. LDS 49408 B -> 3 blocks/CU.
// ---------------------------------------------------------------------------
__global__ __launch_bounds__(256) void fused_kernel(
    const float* __restrict__ ext,  const float* __restrict__ flow,
    const unsigned short* __restrict__ wcat_t,
    const float* __restrict__ boff, const float* __restrict__ battn,
    const unsigned short* __restrict__ wout_t,
    const float* __restrict__ bout,
    const unsigned short* __restrict__ val, float* __restrict__ out) {
  __shared__ float smem[12352];        // 49408 B, phase-overlaid
  const int t    = threadIdx.x;
  const int wv   = t >> 6;
  const int lane = t & 63;
  const int li   = lane & 15, quad = lane >> 4;
  const int qi   = t & 63;
  const int r    = t >> 6;

  // XCD swizzle (as R4)
  const int blk  = blockIdx.x;
  const int lin  = (blk & 7) * 128 + (blk >> 3);
  const int b    = lin >> 8;
  const int tile = lin & 255;
  const int x0   = (tile & 7) * 16;
  const int y0   = (tile >> 3) * 4;
  const int x    = x0 + (qi & 15);
  const int y    = y0 + (qi >> 4);

  // ---------------- phase 1: off/attn GEMM (64q x 192n, K=128) -------------
  unsigned short* a_s  = (unsigned short*)smem;          // [2][64][40] hi/lo
  unsigned short* bw_s = (unsigned short*)(smem + 2560); // [192][40]
  f32x4 acc[12];
#pragma unroll
  for (int n = 0; n < 12; ++n) acc[n] = (f32x4){0.f, 0.f, 0.f, 0.f};

  const float* Eb = ext + (size_t)b * C * HWn;
  for (int ck = 0; ck < 4; ++ck) {
    const int k0 = ck * 32;
    __syncthreads();
    {  // stage ext chunk, split hi/lo bf16, transposed to [q][k]
      int kp = t >> 4;                 // 0..15 -> k = k0+2kp, +1
      int q4 = (t & 15) * 4;
      int yy = q4 >> 4, xx = q4 & 15;
      const float* srcp = Eb + (size_t)(k0 + 2 * kp) * HWn + (y0 + yy) * W + x0 + xx;
      float4 fa = *(const float4*)(srcp);
      float4 fb = *(const float4*)(srcp + HWn);
      const float* pa = &fa.x; const float* pb = &fb.x;
#pragma unroll
      for (int j = 0; j < 4; ++j) {
        unsigned ha = f2bf(pa[j]);
        unsigned hb = f2bf(pb[j]);
        float la = pa[j] - __uint_as_float(ha << 16);
        float lb = pb[j] - __uint_as_float(hb << 16);
        *(unsigned*)&a_s[(q4 + j) * 40 + 2 * kp]        = ha | (hb << 16);
        *(unsigned*)&a_s[2560 + (q4 + j) * 40 + 2 * kp] = pack2bf(la, lb);
      }
    }
#pragma unroll
    for (int it = 0; it < 3; ++it) {   // stage weight chunk [192][32]
      int idx = t + 256 * it;
      int n = idx >> 2, seg = idx & 3;
      *(uint4*)&bw_s[n * 40 + seg * 8] =
          *(const uint4*)(wcat_t + n * 128 + k0 + seg * 8);
    }
    __syncthreads();
    short8 ah = *(const short8*)&a_s[(16 * wv + li) * 40 + quad * 8];
    short8 al = *(const short8*)&a_s[2560 + (16 * wv + li) * 40 + quad * 8];
#pragma unroll
    for (int n = 0; n < 12; ++n) {
      short8 bfr = *(const short8*)&bw_s[(16 * n + li) * 40 + quad * 8];
      acc[n] = __builtin_amdgcn_mfma_f32_16x16x32_bf16(ah, bfr, acc[n], 0, 0, 0);
      acc[n] = __builtin_amdgcn_mfma_f32_16x16x32_bf16(al, bfr, acc[n], 0, 0, 0);
    }
  }

  // redistribute: +bias, C-layout -> proj_s[q][193]
  __syncthreads();
#pragma unroll
  for (int n = 0; n < 12; ++n) {
    int col = 16 * n + li;
    float bias = (col < 128) ? boff[col] : battn[col - 128];
#pragma unroll
    for (int reg = 0; reg < 4; ++reg) {
      int q = 16 * wv + 4 * quad + reg;
      smem[q * 193 + col] = acc[n][reg] + bias;
    }
  }
  __syncthreads();

  // ---------------- phase 2: epilogues + bilinear gather -------------------
  float offa[32];
  float atta[16];
#pragma unroll
  for (int j = 0; j < 32; ++j)
    offa[j] = 10.f * fast_tanh(smem[qi * 193 + 32 * r + j]);
#pragma unroll
  for (int j = 0; j < 16; ++j) atta[j] = smem[qi * 193 + 128 + 16 * r + j];
#pragma unroll
  for (int u = 0; u < 2; ++u) {
    float* a = atta + 8 * u;
    float m = a[0];
#pragma unroll
    for (int p = 1; p < 8; ++p) m = fmaxf(m, a[p]);
    float s = 0.f;
#pragma unroll
    for (int p = 0; p < 8; ++p) { float ev = __expf(a[p] - m); a[p] = ev; s += ev; }
    float inv = 1.f / s;
#pragma unroll
    for (int p = 0; p < 8; ++p) a[p] *= inv;
  }

  const float xb = (float)x + flow[(size_t)b * 2 * HWn + y * W + x];
  const float yb = (float)y + flow[((size_t)b * 2 + 1) * HWn + y * W + x];

  float agg[32];
#pragma unroll
  for (int j = 0; j < 32; ++j) agg[j] = 0.f;
  const unsigned short* valb = val + (size_t)b * NH * HWn * 16;

#pragma unroll
  for (int u = 0; u < 2; ++u) {
    const unsigned short* valh = valb + (size_t)(2 * r + u) * HWn * 16;
    float* aggh = agg + 16 * u;
#pragma unroll
    for (int p = 0; p < 8; ++p) {
      float sx = xb + offa[u * 16 + 2 * p];
      float sy = yb + offa[u * 16 + 2 * p + 1];
      float x0f = floorf(sx), y0f = floorf(sy);
      float wx = sx - x0f, wy = sy - y0f;
      int ix0 = (int)x0f, iy0 = (int)y0f;
      int ix1 = ix0 + 1,  iy1 = iy0 + 1;
      float aw  = atta[u * 8 + p];
      float w00 = aw * (1.f - wx) * (1.f - wy);
      float w10 = aw * wx * (1.f - wy);
      float w01 = aw * (1.f - wx) * wy;
      float w11 = aw * wx * wy;
      if ((unsigned)ix0 >= (unsigned)W) { w00 = 0.f; w01 = 0.f; }
      if ((unsigned)ix1 >= (unsigned)W) { w10 = 0.f; w11 = 0.f; }
      if ((unsigned)iy0 >= (unsigned)H) { w00 = 0.f; w10 = 0.f; }
      if ((unsigned)iy1 >= (unsigned)H) { w01 = 0.f; w11 = 0.f; }
      int x0c = min(max(ix0, 0), W - 1);
      int x1c = min(max(ix1, 0), W - 1);
      int y0c = min(max(iy0, 0), H - 1);
      int y1c = min(max(iy1, 0), H - 1);
      const unsigned short* c00 = valh + (size_t)(y0c * W + x0c) * 16;
      const unsigned short* c10 = valh + (size_t)(y0c * W + x1c) * 16;
      const unsigned short* c01 = valh + (size_t)(y1c * W + x0c) * 16;
      const unsigned short* c11 = valh + (size_t)(y1c * W + x1c) * 16;
#pragma unroll
      for (int cn = 0; cn < 4; ++cn) {
        const unsigned short* cp = (cn == 0) ? c00 : (cn == 1) ? c10
                                  : (cn == 2) ? c01 : c11;
        float wgt = (cn == 0) ? w00 : (cn == 1) ? w10 : (cn == 2) ? w01 : w11;
        uint4 ga = ((const uint4*)cp)[0];
        uint4 gb = ((const uint4*)cp)[1];
        unsigned gs[8] = {ga.x, ga.y, ga.z, ga.w, gb.x, gb.y, gb.z, gb.w};
#pragma unroll
        for (int i = 0; i < 8; ++i) {
          float lo = __uint_as_float(gs[i] << 16);
          float hi = __uint_as_float(gs[i] & 0xFFFF0000u);
          aggh[2 * i]     += wgt * lo;
          aggh[2 * i + 1] += wgt * hi;
        }
      }
    }
  }

  // ---------------- phase 3: out projection via MFMA -----------------------
  __syncthreads();                     // proj_s dead
  unsigned short* ag   = (unsigned short*)smem;          // [64][152] bf16
  unsigned short* w2_s = (unsigned short*)(smem + 4864); // [128][40]
  {
    unsigned pk[16];
#pragma unroll
    for (int i = 0; i < 16; ++i) pk[i] = pack2bf(agg[2 * i], agg[2 * i + 1]);
    uint4* dst = (uint4*)&ag[qi * 152 + 32 * r];
    dst[0] = make_uint4(pk[0],  pk[1],  pk[2],  pk[3]);
    dst[1] = make_uint4(pk[4],  pk[5],  pk[6],  pk[7]);
    dst[2] = make_uint4(pk[8],  pk[9],  pk[10], pk[11]);
    dst[3] = make_uint4(pk[12], pk[13], pk[14], pk[15]);
  }

  f32x4 acc2[8];
#pragma unroll
  for (int n = 0; n < 8; ++n) acc2[n] = (f32x4){0.f, 0.f, 0.f, 0.f};

  for (int ck = 0; ck < 4; ++ck) {
    __syncthreads();
#pragma unroll
    for (int it = 0; it < 2; ++it) {
      int idx = t + 256 * it;
      int n = idx >> 2, seg = idx & 3;
      *(uint4*)&w2_s[n * 40 + seg * 8] =
          *(const uint4*)(wout_t + n * 128 + ck * 32 + seg * 8);
    }
    __syncthreads();
    short8 af = *(const short8*)&ag[(16 * wv + li) * 152 + ck * 32 + quad * 8];
#pragma unroll
    for (int n = 0; n < 8; ++n) {
      short8 bfr = *(const short8*)&w2_s[(16 * n + li) * 40 + quad * 8];
      acc2[n] = __builtin_amdgcn_mfma_f32_16x16x32_bf16(af, bfr, acc2[n], 0, 0, 0);
    }
  }

  // +bias, C-layout -> outs[c][67] fp32 -> coalesced global stores
  __syncthreads();
#pragma unroll
  for (int n = 0; n < 8; ++n) {
    float bias = bout[16 * n + li];
#pragma unroll
    for (int reg = 0; reg < 4; ++reg)
      smem[(16 * n + li) * 67 + 16 * wv + 4 * quad + reg] = acc2[n][reg] + bias;
  }
  __syncthreads();
  float* ob = out + (size_t)b * C * HWn + y * W + x;
#pragma unroll
  for (int j = 0; j < 32; ++j)
    ob[(size_t)(32 * r + j) * HWn] = smem[(32 * r + j) * 67 + qi];
}

extern "C" void kernel_launch(void* const* d_in, const int* in_sizes, int n_in,
                              void* d_out, int out_size, void* d_ws, size_t ws_size,
                              hipStream_t stream) {
  const float* nbr   = (const float*)d_in[0];
  const float* extf  = (const float*)d_in[1];
  const float* flow  = (const float*)d_in[2];
  const float* Woff  = (const float*)d_in[3];
  const float* boff  = (const float*)d_in[4];
  const float* Wattn = (const float*)d_in[5];
  const float* battn = (const float*)d_in[6];
  const float* Wval  = (const float*)d_in[7];
  const float* bval  = (const float*)d_in[8];
  const float* Wout  = (const float*)d_in[9];
  const float* bout  = (const float*)d_in[10];
  float* outp = (float*)d_out;

  unsigned short* val    = (unsigned short*)d_ws;      // B*NH*HW*16 = 16.8 MB
  unsigned short* wcat_t = val + (size_t)B * NH * HWn * 16;
  unsigned short* wval_t = wcat_t + 192 * 128;
  unsigned short* wout_t = wval_t + 128 * 128;

  prep_weights_kernel<<<dim3(2), dim3(256), 0, stream>>>(
      Woff, Wattn, Wval, Wout, wcat_t, wval_t, wout_t);
  val_gemm_kernel<<<dim3(1024), dim3(256), 0, stream>>>(
      nbr, wval_t, bval, val);
  fused_kernel<<<dim3(1024), dim3(256), 0, stream>>>(
      extf, flow, wcat_t, boff, battn, wout_t, bout, val, outp);
}